// Round 1
// baseline (96.803 us; speedup 1.0000x reference)
//
#include <hip/hip_runtime.h>

#define BB 64
#define CC 64
#define TT 8192
#define RR 4
#define NB 8

__global__ __launch_bounds__(256) void rpg_kernel(
    const float* __restrict__ x,
    const float* __restrict__ sigma,
    const float* __restrict__ rho,
    const float* __restrict__ E,
    const float* __restrict__ F,
    float* __restrict__ out)
{
    const int blocksPerB = TT / 256;                 // 32
    const int b = blockIdx.x / blocksPerB;
    const int t = (blockIdx.x % blocksPerB) * 256 + threadIdx.x;

    // per-rank combined scale: (scale/|sigma|) * (scale/|rho|) / R
    const float scale = 8.0f;                        // sqrt(64)
    float g[RR];
    #pragma unroll
    for (int r = 0; r < RR; ++r) {
        float es = scale / (1e-5f + fabsf(sigma[r]));
        float fs = scale / (1e-5f + fabsf(rho[r]));
        g[r] = es * fs * 0.25f;
    }

    float xe[RR][NB];
    float xf[RR][NB];
    #pragma unroll
    for (int r = 0; r < RR; ++r)
        #pragma unroll
        for (int n = 0; n < NB; ++n) { xe[r][n] = 0.0f; xf[r][n] = 0.0f; }

    const float* xp = x + b * CC * TT + t;

    // projection: xe[r][n] = sum_c x[b,c,t] * E[r,c,n]   (E,F wave-uniform -> s_load)
    #pragma unroll 16
    for (int c = 0; c < CC; ++c) {
        const float xv = xp[c * TT];
        const float* Ec = E + (c * NB);              // + r*CC*NB
        const float* Fc = F + (c * NB);
        #pragma unroll
        for (int r = 0; r < RR; ++r) {
            #pragma unroll
            for (int n = 0; n < NB; ++n) {
                xe[r][n] = fmaf(xv, Ec[r * CC * NB + n], xe[r][n]);
                xf[r][n] = fmaf(xv, Fc[r * CC * NB + n], xf[r][n]);
            }
        }
    }

    // fold scale into xe
    #pragma unroll
    for (int r = 0; r < RR; ++r)
        #pragma unroll
        for (int n = 0; n < NB; ++n) xe[r][n] *= g[r];

    // z[n][m] = sum_r xe[r][n]*xf[r][m]; then signed sqrt
    float z[NB][NB];
    float mv = 0.0f;
    #pragma unroll
    for (int n = 0; n < NB; ++n) {
        #pragma unroll
        for (int m = 0; m < NB; ++m) {
            float acc = 0.0f;
            #pragma unroll
            for (int r = 0; r < RR; ++r) acc = fmaf(xe[r][n], xf[r][m], acc);
            float s = sqrtf(fabsf(acc) + 0.01f) - 0.1f;   // s >= ~0
            float v = copysignf(s, acc);
            z[n][m] = v;
            mv = fmaxf(mv, fabsf(v));
        }
    }

    const float rinv = 1.0f / (mv + 1e-5f);

    float* op = out + (b * 64) * TT + t;
    #pragma unroll
    for (int n = 0; n < NB; ++n)
        #pragma unroll
        for (int m = 0; m < NB; ++m)
            op[(n * NB + m) * TT] = z[n][m] * rinv;
}

extern "C" void kernel_launch(void* const* d_in, const int* in_sizes, int n_in,
                              void* d_out, int out_size, void* d_ws, size_t ws_size,
                              hipStream_t stream) {
    const float* x     = (const float*)d_in[0];
    const float* sigma = (const float*)d_in[1];
    const float* rho   = (const float*)d_in[2];
    const float* E     = (const float*)d_in[3];
    const float* F     = (const float*)d_in[4];
    float* out = (float*)d_out;

    dim3 grid(BB * (TT / 256));
    dim3 block(256);
    rpg_kernel<<<grid, block, 0, stream>>>(x, sigma, rho, E, F, out);
}

// Round 2
// 88.197 us; speedup vs baseline: 1.0976x; 1.0976x over previous
//
#include <hip/hip_runtime.h>

#define BB 64
#define CC 64
#define TT 8192
#define RR 4
#define NB 8

__global__ __launch_bounds__(256, 4) void rpg_kernel(
    const float* __restrict__ x,
    const float* __restrict__ sigma,
    const float* __restrict__ rho,
    const float* __restrict__ E,
    const float* __restrict__ F,
    float* __restrict__ out)
{
    const int blocksPerB = TT / 256;                 // 32
    const int b = blockIdx.x / blocksPerB;
    const int t = (blockIdx.x % blocksPerB) * 256 + threadIdx.x;

    // per-rank combined scale: (scale/|sigma|) * (scale/|rho|) / R
    const float scale = 8.0f;                        // sqrt(64)
    float g[RR];
    #pragma unroll
    for (int r = 0; r < RR; ++r) {
        float es = scale / (1e-5f + fabsf(sigma[r]));
        float fs = scale / (1e-5f + fabsf(rho[r]));
        g[r] = es * fs * 0.25f;
    }

    // flat accumulators [r*NB + n] — 64 total, keep resident in VGPRs
    float xe[RR * NB];
    float xf[RR * NB];
    #pragma unroll
    for (int i = 0; i < RR * NB; ++i) { xe[i] = 0.0f; xf[i] = 0.0f; }

    const float* xp = x + b * CC * TT + t;

    // projection: xe[r*8+n] += x[b,c,t] * E[r,c,n]
    // E/F indices are wave-uniform -> s_load; FMA = v_fmac v_acc, s_w, v_xv
    #pragma clang loop distribute(disable)
    #pragma unroll 4
    for (int c = 0; c < CC; ++c) {
        const float xv = xp[c * TT];
        const int base = c * NB;                     // + r*CC*NB
        #pragma unroll
        for (int i = 0; i < RR * NB; ++i) {
            const int r = i >> 3;
            const int n = i & 7;
            xe[i] = fmaf(xv, E[r * (CC * NB) + base + n], xe[i]);
            xf[i] = fmaf(xv, F[r * (CC * NB) + base + n], xf[i]);
        }
    }

    // fold scale into xe
    #pragma unroll
    for (int i = 0; i < RR * NB; ++i) xe[i] *= g[i >> 3];

    // z[n][m] = sum_r xe[r][n]*xf[r][m]; signed sqrt; track max|.|
    float z[NB * NB];
    float mv = 0.0f;
    #pragma unroll
    for (int n = 0; n < NB; ++n) {
        #pragma unroll
        for (int m = 0; m < NB; ++m) {
            float acc = 0.0f;
            #pragma unroll
            for (int r = 0; r < RR; ++r)
                acc = fmaf(xe[r * NB + n], xf[r * NB + m], acc);
            float s = sqrtf(fabsf(acc) + 0.01f) - 0.1f;
            float v = copysignf(s, acc);
            z[n * NB + m] = v;
            mv = fmaxf(mv, fabsf(v));
        }
    }

    const float rinv = 1.0f / (mv + 1e-5f);

    float* op = out + (b * 64) * TT + t;
    #pragma unroll
    for (int k = 0; k < NB * NB; ++k)
        op[k * TT] = z[k] * rinv;
}

extern "C" void kernel_launch(void* const* d_in, const int* in_sizes, int n_in,
                              void* d_out, int out_size, void* d_ws, size_t ws_size,
                              hipStream_t stream) {
    const float* x     = (const float*)d_in[0];
    const float* sigma = (const float*)d_in[1];
    const float* rho   = (const float*)d_in[2];
    const float* E     = (const float*)d_in[3];
    const float* F     = (const float*)d_in[4];
    float* out = (float*)d_out;

    dim3 grid(BB * (TT / 256));
    dim3 block(256);
    rpg_kernel<<<grid, block, 0, stream>>>(x, sigma, rho, E, F, out);
}

// Round 3
// 83.993 us; speedup vs baseline: 1.1525x; 1.0500x over previous
//
#include <hip/hip_runtime.h>

#define BB 64
#define CC 64
#define TT 8192
#define RR 4
#define NB 8

// ---- repack kernel: W[c][s], s<32 -> scaled E, s>=32 -> F ------------------
// W[c*64 + (r*8+n)]      = E[r][c][n] * (8/|sigma_r|)*(8/|rho_r|)*0.25
// W[c*64 + 32 + (r*8+n)] = F[r][c][n]
__global__ __launch_bounds__(256) void rpg_repack(
    const float* __restrict__ sigma,
    const float* __restrict__ rho,
    const float* __restrict__ E,
    const float* __restrict__ F,
    float* __restrict__ W)
{
    const int j = blockIdx.x * 256 + threadIdx.x;
    if (j >= CC * 64) return;
    const int c = j >> 6;
    const int s = j & 63;
    const int r = (s >> 3) & 3;
    const int n = s & 7;
    float val;
    if (s < 32) {
        const float es = 8.0f / (1e-5f + fabsf(sigma[r]));
        const float fs = 8.0f / (1e-5f + fabsf(rho[r]));
        val = E[r * (CC * NB) + c * NB + n] * (es * fs * 0.25f);
    } else {
        val = F[r * (CC * NB) + c * NB + n];
    }
    W[j] = val;
}

// ---- main kernel -----------------------------------------------------------
__global__ __launch_bounds__(256) void rpg_main(
    const float* __restrict__ x,
    const float* __restrict__ W,   // [CC][64], wave-uniform reads -> s_load
    float* __restrict__ out)
{
    const int blocksPerB = TT / 256;                 // 32
    const int b = blockIdx.x / blocksPerB;
    const int t = (blockIdx.x % blocksPerB) * 256 + threadIdx.x;

    float xe[RR * NB];   // E-side, scale pre-folded
    float xf[RR * NB];
    #pragma unroll
    for (int i = 0; i < RR * NB; ++i) { xe[i] = 0.0f; xf[i] = 0.0f; }

    const float* xp = x + b * CC * TT + t;

    #pragma clang loop distribute(disable)
    #pragma unroll 2
    for (int c = 0; c < CC; ++c) {
        const float xv = xp[c * TT];
        const float* __restrict__ w = W + c * 64;    // uniform address
        #pragma unroll
        for (int i = 0; i < RR * NB; ++i)
            xe[i] = fmaf(xv, w[i], xe[i]);
        #pragma unroll
        for (int i = 0; i < RR * NB; ++i)
            xf[i] = fmaf(xv, w[32 + i], xf[i]);
    }

    // z[n][m] = sum_r xe[r][n]*xf[r][m]; signed sqrt; track max|.|
    float z[NB * NB];
    float mv = 0.0f;
    #pragma unroll
    for (int n = 0; n < NB; ++n) {
        #pragma unroll
        for (int m = 0; m < NB; ++m) {
            float acc = 0.0f;
            #pragma unroll
            for (int r = 0; r < RR; ++r)
                acc = fmaf(xe[r * NB + n], xf[r * NB + m], acc);
            float s = sqrtf(fabsf(acc) + 0.01f) - 0.1f;
            float v = copysignf(s, acc);
            z[n * NB + m] = v;
            mv = fmaxf(mv, fabsf(v));
        }
    }

    const float rinv = 1.0f / (mv + 1e-5f);

    float* op = out + (b * 64) * TT + t;
    #pragma unroll
    for (int k = 0; k < NB * NB; ++k)
        op[k * TT] = z[k] * rinv;
}

extern "C" void kernel_launch(void* const* d_in, const int* in_sizes, int n_in,
                              void* d_out, int out_size, void* d_ws, size_t ws_size,
                              hipStream_t stream) {
    const float* x     = (const float*)d_in[0];
    const float* sigma = (const float*)d_in[1];
    const float* rho   = (const float*)d_in[2];
    const float* E     = (const float*)d_in[3];
    const float* F     = (const float*)d_in[4];
    float* out = (float*)d_out;
    float* W   = (float*)d_ws;                       // 4096 floats = 16 KB

    rpg_repack<<<(CC * 64 + 255) / 256, 256, 0, stream>>>(sigma, rho, E, F, W);

    dim3 grid(BB * (TT / 256));
    dim3 block(256);
    rpg_main<<<grid, block, 0, stream>>>(x, W, out);
}

// Round 4
// 65.402 us; speedup vs baseline: 1.4801x; 1.2843x over previous
//
#include <hip/hip_runtime.h>

#define BB 64
#define CC 64
#define TT 8192
#define RR 4
#define NB 8
#define TILE_T 64

typedef __attribute__((ext_vector_type(8))) short bf16x8;
typedef __attribute__((ext_vector_type(4))) float f32x4;

__device__ __forceinline__ unsigned short f32_to_bf16(float f) {
    unsigned u = __float_as_uint(f);
    unsigned r = (u + 0x7FFFu + ((u >> 16) & 1u)) >> 16;
    return (unsigned short)r;
}
__device__ __forceinline__ float bf16_to_f32(unsigned short h) {
    return __uint_as_float(((unsigned)h) << 16);
}

// ---- prep: W[p][c] bf16 hi/lo, p<32 = scaled E (r=p>>3,n=p&7), p>=32 = F ----
__global__ __launch_bounds__(256) void rpg_prep(
    const float* __restrict__ sigma, const float* __restrict__ rho,
    const float* __restrict__ E, const float* __restrict__ F,
    unsigned short* __restrict__ Whi, unsigned short* __restrict__ Wlo)
{
    const int j = blockIdx.x * 256 + threadIdx.x;
    if (j >= 64 * CC) return;
    const int p = j >> 6;
    const int c = j & 63;
    float val;
    if (p < 32) {
        const int r = p >> 3, n = p & 7;
        const float es = 8.0f / (1e-5f + fabsf(sigma[r]));
        const float fs = 8.0f / (1e-5f + fabsf(rho[r]));
        val = E[r * (CC * NB) + c * NB + n] * (es * fs * 0.25f);
    } else {
        const int r = (p - 32) >> 3, n = p & 7;
        val = F[r * (CC * NB) + c * NB + n];
    }
    const unsigned short h = f32_to_bf16(val);
    Whi[p * CC + c] = h;
    Wlo[p * CC + c] = f32_to_bf16(val - bf16_to_f32(h));
}

// ---- main: per block = one b, 64 t columns ---------------------------------
__global__ __launch_bounds__(256) void rpg_main(
    const float* __restrict__ x,
    const unsigned short* __restrict__ Whi,
    const unsigned short* __restrict__ Wlo,
    float* __restrict__ out)
{
    __shared__ float xT[64 * 68];      // [t][c], stride 68 dwords (16B-aligned rows)
    __shared__ float Y[64 * 65];       // [p][t], stride 65 (conflict-free column reads)
    __shared__ float pmax[64 * 4];

    const int tid  = threadIdx.x;
    const int w    = tid >> 6;         // wave = M-tile (16 output channels)
    const int lane = tid & 63;
    const int b    = blockIdx.x >> 7;  // 128 tiles per b
    const int t0   = (blockIdx.x & 127) * TILE_T;

    // A-frags for this wave's M-tile: [ks][hi/lo], 8 bf16 each
    const int am = (lane & 15);
    const int ag = (lane >> 4);
    bf16x8 wa_hi[2], wa_lo[2];
    #pragma unroll
    for (int ks = 0; ks < 2; ++ks) {
        const int p  = w * 16 + am;
        const int c0 = ks * 32 + ag * 8;
        wa_hi[ks] = *(const bf16x8*)(Whi + p * CC + c0);
        wa_lo[ks] = *(const bf16x8*)(Wlo + p * CC + c0);
    }

    // stage x tile transposed: xT[t][c]  (global loads coalesced along t)
    const float* xb = x + (b * CC) * TT + t0;
    #pragma unroll
    for (int i = 0; i < 16; ++i) {
        const int c = w * 16 + i;
        xT[lane * 68 + c] = xb[c * TT + lane];
    }
    __syncthreads();

    // GEMM: Y[p][t] = W[p][c] * xT[t][c]^T   via 16x16x32 bf16 MFMA, 3-pass hi/lo
    #pragma unroll
    for (int nt = 0; nt < 4; ++nt) {
        f32x4 acc = {0.0f, 0.0f, 0.0f, 0.0f};
        const int tl = nt * 16 + am;
        #pragma unroll
        for (int ks = 0; ks < 2; ++ks) {
            const float4 v0 = *(const float4*)&xT[tl * 68 + ks * 32 + ag * 8];
            const float4 v1 = *(const float4*)&xT[tl * 68 + ks * 32 + ag * 8 + 4];
            float f[8] = {v0.x, v0.y, v0.z, v0.w, v1.x, v1.y, v1.z, v1.w};
            bf16x8 xh, xl;
            #pragma unroll
            for (int j = 0; j < 8; ++j) {
                const unsigned short h = f32_to_bf16(f[j]);
                xh[j] = (short)h;
                xl[j] = (short)f32_to_bf16(f[j] - bf16_to_f32(h));
            }
            acc = __builtin_amdgcn_mfma_f32_16x16x32_bf16(wa_hi[ks], xh, acc, 0, 0, 0);
            acc = __builtin_amdgcn_mfma_f32_16x16x32_bf16(wa_hi[ks], xl, acc, 0, 0, 0);
            acc = __builtin_amdgcn_mfma_f32_16x16x32_bf16(wa_lo[ks], xh, acc, 0, 0, 0);
        }
        // D layout: col = lane&15 (t), row = (lane>>4)*4 + r (p within M-tile)
        #pragma unroll
        for (int r = 0; r < 4; ++r) {
            const int p = w * 16 + ag * 4 + r;
            Y[p * 65 + tl] = acc[r];
        }
    }
    __syncthreads();

    // epilogue: thread (t = tid&63, quarter q = tid>>6) handles z rows {2q, 2q+1}
    const int tl = tid & 63;
    const int q  = tid >> 6;

    float xf[RR][NB];
    #pragma unroll
    for (int r = 0; r < RR; ++r)
        #pragma unroll
        for (int m = 0; m < NB; ++m)
            xf[r][m] = Y[(32 + r * NB + m) * 65 + tl];

    float xe[2][RR];
    #pragma unroll
    for (int e = 0; e < 2; ++e) {
        const int n = q * 2 + e;
        #pragma unroll
        for (int r = 0; r < RR; ++r)
            xe[e][r] = Y[(r * NB + n) * 65 + tl];
    }

    float z[16];
    float pm = 0.0f;
    #pragma unroll
    for (int e = 0; e < 2; ++e) {
        #pragma unroll
        for (int m = 0; m < NB; ++m) {
            float acc = 0.0f;
            #pragma unroll
            for (int r = 0; r < RR; ++r)
                acc = fmaf(xe[e][r], xf[r][m], acc);
            float s = sqrtf(fabsf(acc) + 0.01f) - 0.1f;
            float v = copysignf(s, acc);
            z[e * NB + m] = v;
            pm = fmaxf(pm, fabsf(v));
        }
    }
    pmax[tl * 4 + q] = pm;
    __syncthreads();

    const float mv = fmaxf(fmaxf(pmax[tl * 4 + 0], pmax[tl * 4 + 1]),
                           fmaxf(pmax[tl * 4 + 2], pmax[tl * 4 + 3]));
    const float rinv = 1.0f / (mv + 1e-5f);

    float* ob = out + (b * 64) * TT + t0 + tl;
    #pragma unroll
    for (int e = 0; e < 2; ++e) {
        #pragma unroll
        for (int m = 0; m < NB; ++m) {
            const int p = (q * 2 + e) * NB + m;
            ob[p * TT] = z[e * NB + m] * rinv;
        }
    }
}

extern "C" void kernel_launch(void* const* d_in, const int* in_sizes, int n_in,
                              void* d_out, int out_size, void* d_ws, size_t ws_size,
                              hipStream_t stream) {
    const float* x     = (const float*)d_in[0];
    const float* sigma = (const float*)d_in[1];
    const float* rho   = (const float*)d_in[2];
    const float* E     = (const float*)d_in[3];
    const float* F     = (const float*)d_in[4];
    float* out = (float*)d_out;

    unsigned short* Whi = (unsigned short*)d_ws;            // 64*64*2 B = 8 KB
    unsigned short* Wlo = Whi + 64 * CC;                    // next 8 KB

    rpg_prep<<<(64 * CC + 255) / 256, 256, 0, stream>>>(sigma, rho, E, F, Whi, Wlo);

    dim3 grid(BB * (TT / TILE_T));   // 64 * 128 = 8192
    dim3 block(256);
    rpg_main<<<grid, block, 0, stream>>>(x, Whi, Wlo, out);
}

// Round 5
// 52.105 us; speedup vs baseline: 1.8579x; 1.2552x over previous
//
#include <hip/hip_runtime.h>

#define BB 64
#define CC 64
#define TT 8192
#define RR 4
#define NB 8
#define TILE_T 64

typedef __attribute__((ext_vector_type(8))) short bf16x8;
typedef __attribute__((ext_vector_type(4))) float f32x4;

__device__ __forceinline__ unsigned short f32_to_bf16_rn(float f) {
    unsigned u = __float_as_uint(f);
    unsigned r = (u + 0x7FFFu + ((u >> 16) & 1u)) >> 16;
    return (unsigned short)r;
}
__device__ __forceinline__ float bf16_to_f32(unsigned short h) {
    return __uint_as_float(((unsigned)h) << 16);
}

// ---- prep: W[p][c] bf16 hi/lo (round-to-nearest), p<32 = scaled E, p>=32 = F
__global__ __launch_bounds__(256) void rpg_prep(
    const float* __restrict__ sigma, const float* __restrict__ rho,
    const float* __restrict__ E, const float* __restrict__ F,
    unsigned short* __restrict__ Whi, unsigned short* __restrict__ Wlo)
{
    const int j = blockIdx.x * 256 + threadIdx.x;
    if (j >= 64 * CC) return;
    const int p = j >> 6;
    const int c = j & 63;
    float val;
    if (p < 32) {
        const int r = p >> 3, n = p & 7;
        const float es = 8.0f / (1e-5f + fabsf(sigma[r]));
        const float fs = 8.0f / (1e-5f + fabsf(rho[r]));
        val = E[r * (CC * NB) + c * NB + n] * (es * fs * 0.25f);
    } else {
        const int r = (p - 32) >> 3, n = p & 7;
        val = F[r * (CC * NB) + c * NB + n];
    }
    const unsigned short h = f32_to_bf16_rn(val);
    Whi[p * CC + c] = h;
    Wlo[p * CC + c] = f32_to_bf16_rn(val - bf16_to_f32(h));
}

// LDS layout (union across phases):
//  phase 1: xh bf16[64][72] @0 (9216 B), xl bf16[64][72] @9216 (9216 B)
//  phase 2: Y  f32 [64][65] @0 (16640 B), pmax f32[256] @16640 (1024 B)
#define XROW 72           // bf16 row stride (144 B)
#define SMEM_BYTES 18432

__global__ __launch_bounds__(256, 4) void rpg_main(
    const float* __restrict__ x,
    const unsigned short* __restrict__ Whi,
    const unsigned short* __restrict__ Wlo,
    float* __restrict__ out)
{
    __shared__ __align__(16) char smem[SMEM_BYTES];
    unsigned short* xhs = (unsigned short*)smem;
    unsigned short* xls = (unsigned short*)(smem + 9216);
    float* Y    = (float*)smem;
    float* pmax = (float*)(smem + 16640);

    const int tid  = threadIdx.x;
    const int w    = tid >> 6;         // wave id: M-tile (16 W rows) + staging c-chunk
    const int lane = tid & 63;
    const int b    = blockIdx.x >> 7;  // 128 tiles per b
    const int t0   = (blockIdx.x & 127) * TILE_T;

    const int am = (lane & 15);
    const int ag = (lane >> 4);

    // A-frags for this wave's 16 W-rows
    bf16x8 wa_hi[2], wa_lo[2];
    #pragma unroll
    for (int ks = 0; ks < 2; ++ks) {
        const int p  = w * 16 + am;
        const int c0 = ks * 32 + ag * 8;
        wa_hi[ks] = *(const bf16x8*)(Whi + p * CC + c0);
        wa_lo[ks] = *(const bf16x8*)(Wlo + p * CC + c0);
    }

    // ---- stage x column t=lane, c in [w*16, w*16+16), as bf16 hi/lo ---------
    // hi = truncate(f); lo = f - hi (then truncated) -> combined error ~2^-16
    {
        const float* xcol = x + (b * CC) * TT + t0 + lane;
        #pragma unroll
        for (int k = 0; k < 8; ++k) {
            const int c = w * 16 + 2 * k;
            const float f0 = xcol[(c    ) * TT];
            const float f1 = xcol[(c + 1) * TT];
            const unsigned u0 = __float_as_uint(f0), u1 = __float_as_uint(f1);
            const unsigned hw = (u0 >> 16) | (u1 & 0xFFFF0000u);
            const float h0 = __uint_as_float(u0 & 0xFFFF0000u);
            const float h1 = __uint_as_float(u1 & 0xFFFF0000u);
            const unsigned v0 = __float_as_uint(f0 - h0);
            const unsigned v1 = __float_as_uint(f1 - h1);
            const unsigned lw = (v0 >> 16) | (v1 & 0xFFFF0000u);
            *(unsigned*)((char*)xhs + lane * 144 + c * 2) = hw;
            *(unsigned*)((char*)xls + lane * 144 + c * 2) = lw;
        }
    }
    __syncthreads();

    // ---- GEMM: Y[p][t] += W[p][c] * x[c][t], 3-pass bf16 hi/lo --------------
    f32x4 acc[4];
    #pragma unroll
    for (int nt = 0; nt < 4; ++nt) acc[nt] = (f32x4){0.0f, 0.0f, 0.0f, 0.0f};

    #pragma unroll
    for (int nt = 0; nt < 4; ++nt) {
        const int tl = nt * 16 + am;
        #pragma unroll
        for (int ks = 0; ks < 2; ++ks) {
            const int off = tl * 144 + (ks * 32 + ag * 8) * 2;
            const bf16x8 xh = *(const bf16x8*)((char*)xhs + off);
            const bf16x8 xl = *(const bf16x8*)((char*)xls + off);
            acc[nt] = __builtin_amdgcn_mfma_f32_16x16x32_bf16(wa_hi[ks], xh, acc[nt], 0, 0, 0);
            acc[nt] = __builtin_amdgcn_mfma_f32_16x16x32_bf16(wa_hi[ks], xl, acc[nt], 0, 0, 0);
            acc[nt] = __builtin_amdgcn_mfma_f32_16x16x32_bf16(wa_lo[ks], xh, acc[nt], 0, 0, 0);
        }
    }
    __syncthreads();   // xhs/xls dead; Y aliases them

    // D layout: col = lane&15 (t), row = ag*4 + r (p within M-tile)
    #pragma unroll
    for (int nt = 0; nt < 4; ++nt) {
        const int tl = nt * 16 + am;
        #pragma unroll
        for (int r = 0; r < 4; ++r)
            Y[(w * 16 + ag * 4 + r) * 65 + tl] = acc[nt][r];
    }
    __syncthreads();

    // ---- epilogue: thread (t = tid&63, quarter q = tid>>6) -> z rows {2q,2q+1}
    const int tl = tid & 63;
    const int q  = tid >> 6;

    float xf[RR][NB];
    #pragma unroll
    for (int r = 0; r < RR; ++r)
        #pragma unroll
        for (int m = 0; m < NB; ++m)
            xf[r][m] = Y[(32 + r * NB + m) * 65 + tl];

    float xe[2][RR];
    #pragma unroll
    for (int e = 0; e < 2; ++e) {
        const int n = q * 2 + e;
        #pragma unroll
        for (int r = 0; r < RR; ++r)
            xe[e][r] = Y[(r * NB + n) * 65 + tl];
    }

    float z[16];
    float pm = 0.0f;
    #pragma unroll
    for (int e = 0; e < 2; ++e) {
        #pragma unroll
        for (int m = 0; m < NB; ++m) {
            float acc2 = 0.0f;
            #pragma unroll
            for (int r = 0; r < RR; ++r)
                acc2 = fmaf(xe[e][r], xf[r][m], acc2);
            float s = sqrtf(fabsf(acc2) + 0.01f) - 0.1f;
            float v = copysignf(s, acc2);
            z[e * NB + m] = v;
            pm = fmaxf(pm, fabsf(v));
        }
    }
    pmax[tl * 4 + q] = pm;
    __syncthreads();

    const float mv = fmaxf(fmaxf(pmax[tl * 4 + 0], pmax[tl * 4 + 1]),
                           fmaxf(pmax[tl * 4 + 2], pmax[tl * 4 + 3]));
    const float rinv = 1.0f / (mv + 1e-5f);

    float* ob = out + (b * 64) * TT + t0 + tl;
    #pragma unroll
    for (int e = 0; e < 2; ++e) {
        #pragma unroll
        for (int m = 0; m < NB; ++m) {
            const int p = (q * 2 + e) * NB + m;
            ob[p * TT] = z[e * NB + m] * rinv;
        }
    }
}

extern "C" void kernel_launch(void* const* d_in, const int* in_sizes, int n_in,
                              void* d_out, int out_size, void* d_ws, size_t ws_size,
                              hipStream_t stream) {
    const float* x     = (const float*)d_in[0];
    const float* sigma = (const float*)d_in[1];
    const float* rho   = (const float*)d_in[2];
    const float* E     = (const float*)d_in[3];
    const float* F     = (const float*)d_in[4];
    float* out = (float*)d_out;

    unsigned short* Whi = (unsigned short*)d_ws;            // 8 KB
    unsigned short* Wlo = Whi + 64 * CC;                    // 8 KB

    rpg_prep<<<(64 * CC + 255) / 256, 256, 0, stream>>>(sigma, rho, E, F, Whi, Wlo);

    dim3 grid(BB * (TT / TILE_T));   // 8192
    dim3 block(256);
    rpg_main<<<grid, block, 0, stream>>>(x, Whi, Wlo, out);
}

// Round 6
// 51.513 us; speedup vs baseline: 1.8792x; 1.0115x over previous
//
#include <hip/hip_runtime.h>

#define BB 64
#define CC 64
#define TT 8192
#define RR 4
#define NB 8
#define TILE_T 64

typedef __attribute__((ext_vector_type(8))) short bf16x8;
typedef __attribute__((ext_vector_type(4))) float f32x4;
typedef __attribute__((ext_vector_type(4))) int i32x4;

__device__ __forceinline__ unsigned short f32_to_bf16_rn(float f) {
    unsigned u = __float_as_uint(f);
    unsigned r = (u + 0x7FFFu + ((u >> 16) & 1u)) >> 16;
    return (unsigned short)r;
}
__device__ __forceinline__ float bf16_to_f32(unsigned short h) {
    return __uint_as_float(((unsigned)h) << 16);
}

// ---- prep: W[p][c] bf16 hi/lo (round-to-nearest), p<32 = scaled E, p>=32 = F
__global__ __launch_bounds__(256) void rpg_prep(
    const float* __restrict__ sigma, const float* __restrict__ rho,
    const float* __restrict__ E, const float* __restrict__ F,
    unsigned short* __restrict__ Whi, unsigned short* __restrict__ Wlo)
{
    const int j = blockIdx.x * 256 + threadIdx.x;
    if (j >= 64 * CC) return;
    const int p = j >> 6;
    const int c = j & 63;
    float val;
    if (p < 32) {
        const int r = p >> 3, n = p & 7;
        const float es = 8.0f / (1e-5f + fabsf(sigma[r]));
        const float fs = 8.0f / (1e-5f + fabsf(rho[r]));
        val = E[r * (CC * NB) + c * NB + n] * (es * fs * 0.25f);
    } else {
        const int r = (p - 32) >> 3, n = p & 7;
        val = F[r * (CC * NB) + c * NB + n];
    }
    const unsigned short h = f32_to_bf16_rn(val);
    Whi[p * CC + c] = h;
    Wlo[p * CC + c] = f32_to_bf16_rn(val - bf16_to_f32(h));
}

// LDS union:
//  phase 1: xh bf16[64 rows][144 B] @0 (9216 B), xl @9216 (9216 B)
//  phase 2: Y f32[64][68] @0 (17408 B), pmax f32[256] @17408 (1024 B)
#define SMEM_BYTES 18432
#define YST 68

__global__ __launch_bounds__(256, 8) void rpg_main(
    const float* __restrict__ x,
    const unsigned short* __restrict__ Whi,
    const unsigned short* __restrict__ Wlo,
    float* __restrict__ out)
{
    __shared__ __align__(16) char smem[SMEM_BYTES];
    char* xhs = smem;
    char* xls = smem + 9216;
    float* Y    = (float*)smem;
    float* pmax = (float*)(smem + 17408);

    const int tid  = threadIdx.x;
    const int w    = tid >> 6;
    const int lane = tid & 63;
    const int b    = blockIdx.x >> 7;
    const int t0   = (blockIdx.x & 127) * TILE_T;

    const int am = (lane & 15);
    const int ag = (lane >> 4);

    // A-frags for this wave's 16 W rows
    bf16x8 wa_hi[2], wa_lo[2];
    #pragma unroll
    for (int ks = 0; ks < 2; ++ks) {
        const int p  = w * 16 + am;
        const int c0 = ks * 32 + ag * 8;
        wa_hi[ks] = *(const bf16x8*)(Whi + p * CC + c0);
        wa_lo[ks] = *(const bf16x8*)(Wlo + p * CC + c0);
    }

    // ---- stage x column t=lane, c in [w*16, w*16+16), bf16 hi/lo ------------
    // hi = truncate(f); lo = f - hi. Pack 8 dwords each, write 2x b128 per buf
    // (conflict-free: 1024 B per wave-write = LDS data minimum).
    {
        const float* xcol = x + (b * CC) * TT + t0 + lane;
        unsigned hw[8], lw[8];
        #pragma unroll
        for (int k = 0; k < 8; ++k) {
            const int c = w * 16 + 2 * k;
            const float f0 = xcol[(c    ) * TT];
            const float f1 = xcol[(c + 1) * TT];
            const unsigned u0 = __float_as_uint(f0), u1 = __float_as_uint(f1);
            hw[k] = (u0 >> 16) | (u1 & 0xFFFF0000u);
            const float h0 = __uint_as_float(u0 & 0xFFFF0000u);
            const float h1 = __uint_as_float(u1 & 0xFFFF0000u);
            lw[k] = (__float_as_uint(f0 - h0) >> 16) | (__float_as_uint(f1 - h1) & 0xFFFF0000u);
        }
        char* hrow = xhs + lane * 144 + w * 32;
        char* lrow = xls + lane * 144 + w * 32;
        *(i32x4*)(hrow     ) = (i32x4){(int)hw[0], (int)hw[1], (int)hw[2], (int)hw[3]};
        *(i32x4*)(hrow + 16) = (i32x4){(int)hw[4], (int)hw[5], (int)hw[6], (int)hw[7]};
        *(i32x4*)(lrow     ) = (i32x4){(int)lw[0], (int)lw[1], (int)lw[2], (int)lw[3]};
        *(i32x4*)(lrow + 16) = (i32x4){(int)lw[4], (int)lw[5], (int)lw[6], (int)lw[7]};
    }
    __syncthreads();

    // ---- GEMM: Y[p][t] = W[p][c] * x[c][t], 3-pass bf16 hi/lo ---------------
    f32x4 acc[4];
    #pragma unroll
    for (int nt = 0; nt < 4; ++nt) acc[nt] = (f32x4){0.0f, 0.0f, 0.0f, 0.0f};

    #pragma unroll
    for (int nt = 0; nt < 4; ++nt) {
        const int tl = nt * 16 + am;
        #pragma unroll
        for (int ks = 0; ks < 2; ++ks) {
            const int off = tl * 144 + (ks * 32 + ag * 8) * 2;
            const bf16x8 xh = *(const bf16x8*)(xhs + off);
            const bf16x8 xl = *(const bf16x8*)(xls + off);
            acc[nt] = __builtin_amdgcn_mfma_f32_16x16x32_bf16(wa_hi[ks], xh, acc[nt], 0, 0, 0);
            acc[nt] = __builtin_amdgcn_mfma_f32_16x16x32_bf16(wa_hi[ks], xl, acc[nt], 0, 0, 0);
            acc[nt] = __builtin_amdgcn_mfma_f32_16x16x32_bf16(wa_lo[ks], xh, acc[nt], 0, 0, 0);
        }
    }
    __syncthreads();   // xhs/xls dead; Y aliases them

    // D layout: col = am (t), row = ag*4 + r. Y stride 68 -> bank-free writes
    #pragma unroll
    for (int nt = 0; nt < 4; ++nt) {
        const int tl = nt * 16 + am;
        #pragma unroll
        for (int r = 0; r < 4; ++r)
            Y[(w * 16 + ag * 4 + r) * YST + tl] = acc[nt][r];
    }
    __syncthreads();

    // ---- epilogue: thread (t = tid&63, quarter q = tid>>6) -> z rows {2q,2q+1}
    const int tl = tid & 63;
    const int q  = tid >> 6;

    float xf[RR][NB];
    #pragma unroll
    for (int r = 0; r < RR; ++r)
        #pragma unroll
        for (int m = 0; m < NB; ++m)
            xf[r][m] = Y[(32 + r * NB + m) * YST + tl];

    float xe[2][RR];
    #pragma unroll
    for (int e = 0; e < 2; ++e) {
        const int n = q * 2 + e;
        #pragma unroll
        for (int r = 0; r < RR; ++r)
            xe[e][r] = Y[(r * NB + n) * YST + tl];
    }

    float z[16];
    float pm = 0.0f;
    #pragma unroll
    for (int e = 0; e < 2; ++e) {
        #pragma unroll
        for (int m = 0; m < NB; ++m) {
            float acc2 = 0.0f;
            #pragma unroll
            for (int r = 0; r < RR; ++r)
                acc2 = fmaf(xe[e][r], xf[r][m], acc2);
            float s = __builtin_amdgcn_sqrtf(fabsf(acc2) + 0.01f) - 0.1f;
            float v = copysignf(s, acc2);
            z[e * NB + m] = v;
            pm = fmaxf(pm, fabsf(v));
        }
    }
    pmax[q * 64 + tl] = pm;
    __syncthreads();

    const float mv = fmaxf(fmaxf(pmax[tl], pmax[64 + tl]),
                           fmaxf(pmax[128 + tl], pmax[192 + tl]));
    const float rinv = __builtin_amdgcn_rcpf(mv + 1e-5f);

    float* ob = out + (b * 64) * TT + t0 + tl;
    #pragma unroll
    for (int e = 0; e < 2; ++e) {
        #pragma unroll
        for (int m = 0; m < NB; ++m) {
            const int p = (q * 2 + e) * NB + m;
            ob[p * TT] = z[e * NB + m] * rinv;
        }
    }
}

extern "C" void kernel_launch(void* const* d_in, const int* in_sizes, int n_in,
                              void* d_out, int out_size, void* d_ws, size_t ws_size,
                              hipStream_t stream) {
    const float* x     = (const float*)d_in[0];
    const float* sigma = (const float*)d_in[1];
    const float* rho   = (const float*)d_in[2];
    const float* E     = (const float*)d_in[3];
    const float* F     = (const float*)d_in[4];
    float* out = (float*)d_out;

    unsigned short* Whi = (unsigned short*)d_ws;            // 8 KB
    unsigned short* Wlo = Whi + 64 * CC;                    // 8 KB

    rpg_prep<<<(64 * CC + 255) / 256, 256, 0, stream>>>(sigma, rho, E, F, Whi, Wlo);

    dim3 grid(BB * (TT / TILE_T));   // 8192
    dim3 block(256);
    rpg_main<<<grid, block, 0, stream>>>(x, Whi, Wlo, out);
}